// Round 8
// baseline (271.650 us; speedup 1.0000x reference)
//
#include <hip/hip_runtime.h>
#include <math.h>

#define NODES   62
#define DEG     16
#define EPN     17                  // edges per node incl. self-loop
#define EPG     (NODES*EPN)         // 1054
#define NGRAPH  4096
#define NTOT    (NGRAPH*NODES)      // 253952
#define FIN     32
#define HIDC    64
#define XS      72                  // bf16 row stride (144B = 9*16 -> b128 aligned)
#define WS      40                  // bf16 row stride for phase-a operand tiles
#define GPB     16                  // graphs per bnred block

typedef __attribute__((ext_vector_type(8))) short bf16x8;   // MFMA A/B frag
typedef __attribute__((ext_vector_type(4))) float f32x4;    // MFMA C/D frag

__device__ __forceinline__ unsigned short bf16r(float f) {   // f32 -> bf16 RNE
    unsigned int u = __float_as_uint(f);
    u += 0x7fffu + ((u >> 16) & 1u);
    return (unsigned short)(u >> 16);
}
__device__ __forceinline__ unsigned int pk2(float a, float b) {
    return (unsigned int)bf16r(a) | ((unsigned int)bf16r(b) << 16);
}
__device__ __forceinline__ float blo(unsigned int d) { return __uint_as_float(d << 16); }
__device__ __forceinline__ float bhi(unsigned int d) { return __uint_as_float(d & 0xffff0000u); }
__device__ __forceinline__ float lrelu(float z) { return fmaxf(z, 0.2f*z); }

// ---------------------------------------------------------------------------
// Kernel A: GATv2 layer 1, one block (256 thr) per 62-node graph.
// phase-a (x@Wl, x@Wr) on MFMA; alpha edge-parallel VALU; softmax quads;
// aggregation h = P @ XL on MFMA (dense bf16 P built in LDS, f32 accumulation
// of duplicate edges). h written bf16. BN partials moved to bnred_kernel.
// ---------------------------------------------------------------------------
__global__ __launch_bounds__(256, 3) void gat1_kernel(
    const float* __restrict__ x, const int* __restrict__ esrc,
    const float* __restrict__ Wl, const float* __restrict__ bl,
    const float* __restrict__ Wr, const float* __restrict__ br,
    const float* __restrict__ att, const float* __restrict__ bias,
    unsigned short* __restrict__ hb)
{
    // overlaid region: staging (xbf|wlT|wrT) then (xlt|Pb)
    __shared__ __align__(16) unsigned char R0[18432];
    unsigned short* xbf = (unsigned short*)R0;              // [64][WS] phase-a A
    unsigned short* wlT = (unsigned short*)(R0 + 5120);     // [64][WS] Wl^T
    unsigned short* wrT = (unsigned short*)(R0 + 10240);    // [64][WS] Wr^T
    unsigned short* xlt = (unsigned short*)R0;              // [64][XS] XL^T (after S2)
    unsigned short* Pb  = (unsigned short*)(R0 + 9216);     // [64][XS] dense P (after S5)

    __shared__ float blL[HIDC], brL[HIDC];                  // 512 B
    __shared__ __align__(16) unsigned int attL[32];         // 128 B
    __shared__ unsigned short eS[EPG];                      // 2108 B
    __shared__ float aw[EPG];                               // 4216 B
    __shared__ __align__(16) unsigned short xlb[64*XS];     // 9216 B
    __shared__ __align__(16) unsigned short xrb[64*XS];     // 9216 B  (total ~43.8 KB)

    const int tid   = threadIdx.x;
    const int g     = blockIdx.x;
    const int nbase = g * NODES;

    // ---- stage x -> bf16 (rows 62,63 zeroed) ----
    {
        const float2* xg = (const float2*)(x + (size_t)nbase * FIN);
        for (int i = tid; i < 64*16; i += 256) {
            const int n = i >> 4, c2 = i & 15;
            unsigned int pkv = 0u;
            if (n < NODES) {
                const float2 v = xg[i];
                pkv = pk2(v.x, v.y);
            }
            ((unsigned int*)xbf)[n*(WS/2) + c2] = pkv;
        }
    }
    // ---- stage Wl^T, Wr^T ([col][k]) ----
    for (int i = tid; i < FIN*HIDC; i += 256) {
        const int k = i >> 6, c = i & 63;
        wlT[c*WS + k] = bf16r(Wl[i]);
        wrT[c*WS + k] = bf16r(Wr[i]);
    }
    if (tid < HIDC) { blL[tid] = bl[tid]; brL[tid] = br[tid]; }
    if (tid < 32)
        attL[tid] = pk2(att[2*tid], att[2*tid+1]);

    // ---- stage edge table (edge i = node i/17, slot i%17; slot 16 = self) ----
    const int* eg = esrc + (size_t)nbase * DEG;
    for (int i = tid; i < EPG; i += 256) {
        const unsigned int d = ((unsigned int)i * 61681u) >> 20;   // i/17 exact
        const int j = i - (int)d * EPN;
        const int s = (j < DEG) ? (eg[(int)d*DEG + j] - nbase) : (int)d;
        eS[i] = (unsigned short)s;
    }
    __syncthreads();                                        // S1

    const int wv  = tid >> 6;
    const int l   = tid & 63;
    const int r16 = l & 15;
    const int kg  = l >> 4;

    // ---- phase-a MFMA (all operand reads before S2; results in regs) ----
    f32x4 aL[4], aR[4];
    {
        const bf16x8 afr = *(const bf16x8*)(xbf + (wv*16 + r16)*WS + kg*8);
        const f32x4 zz = {0.f, 0.f, 0.f, 0.f};
#pragma unroll
        for (int ct = 0; ct < 4; ++ct) {
            const bf16x8 bL = *(const bf16x8*)(wlT + (ct*16 + r16)*WS + kg*8);
            aL[ct] = __builtin_amdgcn_mfma_f32_16x16x32_bf16(afr, bL, zz, 0, 0, 0);
            const bf16x8 bR = *(const bf16x8*)(wrT + (ct*16 + r16)*WS + kg*8);
            aR[ct] = __builtin_amdgcn_mfma_f32_16x16x32_bf16(afr, bR, zz, 0, 0, 0);
        }
    }
    __syncthreads();                                        // S2 (staging dead)

    // ---- epilogue: D[row=wv*16+kg*4+j][col=ct*16+r16] -> xlb, xrb, xlt ----
#pragma unroll
    for (int ct = 0; ct < 4; ++ct) {
        const int col = ct*16 + r16;
        const float bLc = blL[col], bRc = brL[col];
#pragma unroll
        for (int j = 0; j < 4; ++j) {
            const int row = wv*16 + kg*4 + j;
            const unsigned short xv = bf16r(aL[ct][j] + bLc);
            xlb[row*XS + col] = xv;
            xlt[col*XS + row] = xv;
            xrb[row*XS + col] = bf16r(aR[ct][j] + bRc);
        }
    }
    // att -> 32 VGPRs
    uint4 apr[8];
#pragma unroll
    for (int q = 0; q < 8; ++q) apr[q] = ((const uint4*)attL)[q];
    __syncthreads();                                        // S3

    // ---- alpha: one lane per edge, serial over 64 channels ----
    for (int i = tid; i < EPG; i += 256) {
        const unsigned int d = ((unsigned int)i * 61681u) >> 20;
        const int s = eS[i];
        const uint4* lp = (const uint4*)(xlb + s*XS);
        const uint4* rp = (const uint4*)(xrb + (int)d*XS);
        float acc = 0.f;
#pragma unroll
        for (int q = 0; q < 8; ++q) {
            const uint4 lv = lp[q];
            const uint4 rv = rp[q];
            const uint4 ap = apr[q];
            float z;
            z = blo(lv.x)+blo(rv.x); acc += blo(ap.x) * lrelu(z);
            z = bhi(lv.x)+bhi(rv.x); acc += bhi(ap.x) * lrelu(z);
            z = blo(lv.y)+blo(rv.y); acc += blo(ap.y) * lrelu(z);
            z = bhi(lv.y)+bhi(rv.y); acc += bhi(ap.y) * lrelu(z);
            z = blo(lv.z)+blo(rv.z); acc += blo(ap.z) * lrelu(z);
            z = bhi(lv.z)+bhi(rv.z); acc += bhi(ap.z) * lrelu(z);
            z = blo(lv.w)+blo(rv.w); acc += blo(ap.w) * lrelu(z);
            z = bhi(lv.w)+bhi(rv.w); acc += bhi(ap.w) * lrelu(z);
        }
        aw[i] = acc;
    }
    __syncthreads();                                        // S4

    // ---- softmax per node: 4-lane quads, edges split 4/4/4/5; aw -> f32 w ----
    {
        const int node = tid >> 2, sub = tid & 3;
        if (node < NODES) {
            const int base = node*EPN + sub*4;
            float a0 = aw[base+0], a1 = aw[base+1];
            float a2 = aw[base+2], a3 = aw[base+3];
            const bool h5 = (sub == 3);
            float a4 = h5 ? aw[base+4] : -1e30f;
            float m = fmaxf(fmaxf(fmaxf(a0,a1), fmaxf(a2,a3)), a4);
            m = fmaxf(m, __shfl_xor(m,1));
            m = fmaxf(m, __shfl_xor(m,2));
            a0 = __expf(a0-m); a1 = __expf(a1-m); a2 = __expf(a2-m); a3 = __expf(a3-m);
            a4 = h5 ? __expf(a4-m) : 0.f;
            float ss = a0+a1+a2+a3+a4;
            ss += __shfl_xor(ss,1);
            ss += __shfl_xor(ss,2);
            const float inv = 1.f/(ss + 1e-16f);
            aw[base+0] = a0*inv; aw[base+1] = a1*inv;
            aw[base+2] = a2*inv; aw[base+3] = a3*inv;
            if (h5) aw[base+4] = a4*inv;
        }
    }
    __syncthreads();                                        // S5

    // ---- build dense P (bf16): 16 lanes/node, each owns 4 columns.
    //      f32 accumulation handles duplicate (s,d) edges exactly. ----
    {
        const int c0 = (tid & 15) * 4;
        const int gr = tid >> 4;
#pragma unroll
        for (int p = 0; p < 4; ++p) {
            const int node = gr*4 + p;
            float a0=0.f, a1=0.f, a2=0.f, a3=0.f;
            if (node < NODES) {
#pragma unroll
                for (int e = 0; e < EPN; ++e) {
                    const float w = aw[node*EPN + e];      // 16-lane broadcast
                    const int   s = eS[node*EPN + e];
                    a0 += (s == c0+0) ? w : 0.f;
                    a1 += (s == c0+1) ? w : 0.f;
                    a2 += (s == c0+2) ? w : 0.f;
                    a3 += (s == c0+3) ? w : 0.f;
                }
            }
            uint2 pv; pv.x = pk2(a0, a1); pv.y = pk2(a2, a3);
            *(uint2*)(Pb + node*XS + c0) = pv;             // rows 62,63 zeroed
        }
    }
    __syncthreads();                                        // S6

    // ---- aggregation on MFMA: hT[c][d] = sum_s XLT[c][s] * P[d][s] ----
    {
        const bf16x8 bk0 = *(const bf16x8*)(Pb + (wv*16 + r16)*XS + 0  + kg*8);
        const bf16x8 bk1 = *(const bf16x8*)(Pb + (wv*16 + r16)*XS + 32 + kg*8);
        const f32x4 zz = {0.f, 0.f, 0.f, 0.f};
        const int d = wv*16 + r16;
#pragma unroll
        for (int ct = 0; ct < 4; ++ct) {
            const bf16x8 ak0 = *(const bf16x8*)(xlt + (ct*16 + r16)*XS + 0  + kg*8);
            const bf16x8 ak1 = *(const bf16x8*)(xlt + (ct*16 + r16)*XS + 32 + kg*8);
            f32x4 d2 = __builtin_amdgcn_mfma_f32_16x16x32_bf16(ak0, bk0, zz, 0, 0, 0);
            d2 = __builtin_amdgcn_mfma_f32_16x16x32_bf16(ak1, bk1, d2, 0, 0, 0);
            if (d < NODES) {
                const float4 bs = *(const float4*)(bias + ct*16 + kg*4);
                uint2 hv;
                hv.x = pk2(d2[0] + bs.x, d2[1] + bs.y);
                hv.y = pk2(d2[2] + bs.z, d2[3] + bs.w);
                *(uint2*)(hb + (size_t)(nbase + d)*HIDC + ct*16 + kg*4) = hv;
            }
        }
    }
}

// ---------------------------------------------------------------------------
// Kernel B1: BN partials straight from bf16 h. 256 blocks x 16 graphs each.
// part[b][0:64]=sum, part[b][64:128]=sumsq.
// ---------------------------------------------------------------------------
__global__ __launch_bounds__(256) void bnred_kernel(
    const unsigned short* __restrict__ hb, float* __restrict__ part)
{
    __shared__ float rs[16][68], rq[16][68];
    const int tid = threadIdx.x;
    const int b   = blockIdx.x;
    const int rg  = tid >> 4;
    const int c4  = (tid & 15) * 4;
    const unsigned short* base = hb + (size_t)b * GPB * NODES * HIDC;

    float s0=0.f,s1=0.f,s2=0.f,s3=0.f, q0=0.f,q1=0.f,q2=0.f,q3=0.f;
    for (int r = rg; r < GPB*NODES; r += 16) {
        const uint2 v = *(const uint2*)(base + (size_t)r*HIDC + c4);
        const float f0 = blo(v.x), f1 = bhi(v.x), f2 = blo(v.y), f3 = bhi(v.y);
        s0 += f0; s1 += f1; s2 += f2; s3 += f3;
        q0 += f0*f0; q1 += f1*f1; q2 += f2*f2; q3 += f3*f3;
    }
    rs[rg][c4+0]=s0; rs[rg][c4+1]=s1; rs[rg][c4+2]=s2; rs[rg][c4+3]=s3;
    rq[rg][c4+0]=q0; rq[rg][c4+1]=q1; rq[rg][c4+2]=q2; rq[rg][c4+3]=q3;
    __syncthreads();
    if (tid < 128) {
        const int sel = tid >> 6, c = tid & 63;
        float s = 0.f;
#pragma unroll
        for (int gi = 0; gi < 16; ++gi)
            s += sel ? rq[gi][c] : rs[gi][c];
        part[(size_t)b*128 + tid] = s;
    }
}

// ---------------------------------------------------------------------------
// Kernel B2: final fold. part[256][128] -> BN folded into layer-2 weights.
// fw[0:64]=sc*Wl2, fw[64:128]=sc*Wr2, fw[128]=bl2', fw[129]=br2'
// ---------------------------------------------------------------------------
__global__ __launch_bounds__(256) void bnfold_kernel(
    const float* __restrict__ part,
    const float* __restrict__ gamma, const float* __restrict__ beta,
    const float* __restrict__ Wl2, const float* __restrict__ bl2,
    const float* __restrict__ Wr2, const float* __restrict__ br2,
    float* __restrict__ fw)
{
    __shared__ float hred[2][128];
    __shared__ float gs[128];
    __shared__ float tmp[128];
    const int tid = threadIdx.x;
    const int ch = tid & 127, hg = tid >> 7;
    float s = 0.f;
    for (int r = hg; r < 256; r += 2) s += part[(size_t)r*128 + ch];
    hred[hg][ch] = s;
    __syncthreads();
    if (tid < 128) gs[tid] = hred[0][tid] + hred[1][tid];
    __syncthreads();
    if (tid < HIDC) {
        const float invN = 1.f / (float)NTOT;
        const float mu  = gs[tid] * invN;
        const float var = gs[HIDC + tid] * invN - mu*mu;
        const float sc  = gamma[tid] * rsqrtf(var + 1e-5f);
        const float sh  = beta[tid] - mu * sc;
        fw[tid]        = sc * Wl2[tid];
        fw[HIDC + tid] = sc * Wr2[tid];
        tmp[tid]        = sh * Wl2[tid];
        tmp[HIDC + tid] = sh * Wr2[tid];
    }
    __syncthreads();
    if (tid < 64) {
        float aL2 = tmp[tid], aR2 = tmp[64 + tid];
#pragma unroll
        for (int msk = 1; msk < 64; msk <<= 1) {
            aL2 += __shfl_xor(aL2, msk);
            aR2 += __shfl_xor(aR2, msk);
        }
        if (tid == 0) { fw[128] = aL2 + bl2[0]; fw[129] = aR2 + br2[0]; }
    }
}

// ---------------------------------------------------------------------------
// Kernel C: GATv2 layer 2 + exact GELU. 4 graphs/block, one wave each.
// bf16 h input. No tight VGPR cap (round-2 lesson).
// ---------------------------------------------------------------------------
__global__ __launch_bounds__(256, 2) void gat2_kernel(
    const unsigned short* __restrict__ hb, const int* __restrict__ esrc,
    const float* __restrict__ fw, const float* __restrict__ att2,
    const float* __restrict__ bias2, float* __restrict__ out)
{
    __shared__ float fwL[130];
    __shared__ float xl2s[4][64], xr2s[4][64];
    __shared__ unsigned short srcs[4][NODES*DEG];

    const int tid = threadIdx.x;
    const int wv  = tid >> 6, l = tid & 63;
    const int g   = blockIdx.x*4 + wv;
    const int nbase = g * NODES;

    if (tid < 130) fwL[tid] = fw[tid];
    const int* eg = esrc + (size_t)nbase * DEG;
    for (int i = l; i < NODES*DEG; i += 64)
        srcs[wv][i] = (unsigned short)(eg[i] - nbase);
    __syncthreads();

    const int q = l >> 2, sub = l & 3;     // quad per node

    // xl2/xr2: quad per node, 16 channels per lane (bf16 h), 4 rounds
#pragma unroll
    for (int r = 0; r < 4; ++r) {
        const int n = r*16 + q;
        if (n < NODES) {
            const uint4* hp = (const uint4*)(hb + (size_t)(nbase + n)*HIDC + sub*16);
            const uint4 v0 = hp[0];
            const uint4 v1 = hp[1];
            float al = 0.f, ar = 0.f;
            const int cb = sub*16;
            const unsigned int w8[8] = {v0.x,v0.y,v0.z,v0.w,v1.x,v1.y,v1.z,v1.w};
#pragma unroll
            for (int t = 0; t < 8; ++t) {
                const float f0 = blo(w8[t]), f1 = bhi(w8[t]);
                al += f0*fwL[cb+2*t]    + f1*fwL[cb+2*t+1];
                ar += f0*fwL[64+cb+2*t] + f1*fwL[64+cb+2*t+1];
            }
            al += __shfl_xor(al,1); al += __shfl_xor(al,2);
            ar += __shfl_xor(ar,1); ar += __shfl_xor(ar,2);
            if (sub == 0) { xl2s[wv][n] = al + fwL[128]; xr2s[wv][n] = ar + fwL[129]; }
        }
    }
    __syncthreads();

    // attention + aggregation: quad per node, edges split 4/4/4/(4+self)
    const float a2v = att2[0];
    const float b2v = bias2[0];
#pragma unroll
    for (int r = 0; r < 4; ++r) {
        const int n = r*16 + q;
        if (n < NODES) {
            const float xr = xr2s[wv][n];
            const int jb = sub*4;
            const int s0 = srcs[wv][n*DEG + jb+0];
            const int s1 = srcs[wv][n*DEG + jb+1];
            const int s2 = srcs[wv][n*DEG + jb+2];
            const int s3 = srcs[wv][n*DEG + jb+3];
            const bool h5 = (sub == 3);
            const float x0 = xl2s[wv][s0], x1 = xl2s[wv][s1];
            const float x2 = xl2s[wv][s2], x3 = xl2s[wv][s3];
            const float x4 = xl2s[wv][n];                  // self loop
            const float v0 = lrelu(x0+xr)*a2v;
            const float v1 = lrelu(x1+xr)*a2v;
            const float v2 = lrelu(x2+xr)*a2v;
            const float v3 = lrelu(x3+xr)*a2v;
            const float v4 = h5 ? lrelu(x4+xr)*a2v : -1e30f;
            float m = fmaxf(fmaxf(fmaxf(v0,v1), fmaxf(v2,v3)), v4);
            m = fmaxf(m, __shfl_xor(m,1));
            m = fmaxf(m, __shfl_xor(m,2));
            const float e0 = __expf(v0-m), e1 = __expf(v1-m);
            const float e2 = __expf(v2-m), e3 = __expf(v3-m);
            const float e4 = h5 ? __expf(v4-m) : 0.f;
            float ss = e0+e1+e2+e3+e4;
            float ac = e0*x0 + e1*x1 + e2*x2 + e3*x3 + e4*x4;
            ss += __shfl_xor(ss,1); ss += __shfl_xor(ss,2);
            ac += __shfl_xor(ac,1); ac += __shfl_xor(ac,2);
            if (sub == 0) {
                const float o = ac/(ss + 1e-16f) + b2v;
                out[(size_t)g*NODES + n] = 0.5f*o*(1.f + erff(o*0.70710678118654752f));
            }
        }
    }
}

extern "C" void kernel_launch(void* const* d_in, const int* in_sizes, int n_in,
                              void* d_out, int out_size, void* d_ws, size_t ws_size,
                              hipStream_t stream) {
    const float* x     = (const float*)d_in[0];
    const int*   edge  = (const int*)d_in[1];     // [2,E]; src = first E
    const float* Wl1   = (const float*)d_in[2];
    const float* bl1   = (const float*)d_in[3];
    const float* Wr1   = (const float*)d_in[4];
    const float* br1   = (const float*)d_in[5];
    const float* att1  = (const float*)d_in[6];
    const float* bias1 = (const float*)d_in[7];
    const float* gamma = (const float*)d_in[8];
    const float* beta  = (const float*)d_in[9];
    const float* Wl2   = (const float*)d_in[10];
    const float* bl2   = (const float*)d_in[11];
    const float* Wr2   = (const float*)d_in[12];
    const float* br2   = (const float*)d_in[13];
    const float* att2  = (const float*)d_in[14];
    const float* bias2 = (const float*)d_in[15];
    float* out = (float*)d_out;

    unsigned short* hb = (unsigned short*)d_ws;                 // NTOT*64 bf16
    float* part = (float*)((char*)d_ws + (size_t)NTOT*HIDC*2);  // 256*128 f32
    float* fw   = part + (size_t)256*128;                       // 130 f32

    gat1_kernel<<<NGRAPH, 256, 0, stream>>>(x, edge, Wl1, bl1, Wr1, br1,
                                            att1, bias1, hb);
    bnred_kernel<<<NGRAPH/GPB, 256, 0, stream>>>(hb, part);
    bnfold_kernel<<<1, 256, 0, stream>>>(part, gamma, beta, Wl2, bl2, Wr2, br2, fw);
    gat2_kernel<<<NGRAPH/4, 256, 0, stream>>>(hb, edge, fw, att2, bias2, out);
}